// Round 10
// baseline (258.069 us; speedup 1.0000x reference)
//
#include <hip/hip_runtime.h>

typedef unsigned short ushort_t;
typedef __attribute__((ext_vector_type(8))) short short8;
typedef __attribute__((ext_vector_type(4))) float floatx4;

#define DD 256
#define LL 3
#define GG 4
#define KK 128
#define UU 64
#define OUTN 10
#define HSTRIDE 264   // 256 + 8 bf16 pad; 528B row stride
#define MROWS 128     // rows per block
#define NT 2          // 16-col tiles per wave (8 waves x 32 cols = 256)

__device__ __forceinline__ ushort_t f2bf(float f) {
  unsigned u = __builtin_bit_cast(unsigned, f);
  u = (u + 0x7FFFu + ((u >> 16) & 1u)) >> 16;
  return (ushort_t)u;
}

// pack two f32 -> two bf16: 2 adds + 1 v_perm_b32
__device__ __forceinline__ unsigned pack_bf2(float lo, float hi) {
  unsigned a = __builtin_bit_cast(unsigned, hi) + 0x8000u;
  unsigned b = __builtin_bit_cast(unsigned, lo) + 0x8000u;
  return __builtin_amdgcn_perm(a, b, 0x07060302u);
}

// tanh(x) = 1 - 2/(e^{2x}+1); branch-free, exact at overflow
__device__ __forceinline__ float fast_tanh(float x) {
  float e = __builtin_amdgcn_exp2f(x * 2.885390081777927f);
  return __builtin_fmaf(-2.0f, __builtin_amdgcn_rcpf(e + 1.0f), 1.0f);
}

// FRAG-MAJOR operand layouts (r9, kept):
// ATF[l][T][ks][lane][8] bf16, T = n>>4 (16 col-tiles), ks = k>>5,
// lane = quad*16 + l16, elem j -> (n = T*16 + l16, k = ks*32 + quad*8 + j).
// A-fragment load in fused = one contiguous 1KB global_load_dwordx4 per wave.
// WF[ks][lane][8] likewise for W_out^T (o = l16 rows, o<10 else 0).
__global__ __launch_bounds__(256) void prep_kernel(
    const int* __restrict__ idx, const float* __restrict__ W,
    const float* __restrict__ Wout, ushort_t* __restrict__ ATF,
    ushort_t* __restrict__ WF) {
  int b = blockIdx.x;
  int t = threadIdx.x;
  if (b < LL * DD) {
    int l = b >> 8, n = b & 255, g = n >> 6, u = n & 63;
    __shared__ int sidx[KK];
    __shared__ float sw[KK];
    if (t < KK) {
      sidx[t] = idx[(l * GG + g) * KK + t];
      sw[t]   = W[((size_t)((l * GG + g) * KK + t)) * UU + u];
    }
    __syncthreads();
    float s = 0.f;
#pragma unroll 8
    for (int j = 0; j < KK; j++) s += (sidx[j] == t) ? sw[j] : 0.f;
    // scatter into frag-major position (k = t)
    int T = n >> 4, nl = n & 15;
    int ks = t >> 5, q = (t >> 3) & 3, j = t & 7;
    ATF[((((l * 16 + T) * 8 + ks) * 64) + q * 16 + nl) * 8 + j] = f2bf(s);
  } else {
    int e2 = (b - LL * DD) * 256 + t;
    int n = e2 >> 8, k = e2 & 255;   // n = output col (o), k = input dim
    int ks = k >> 5, q = (k >> 3) & 3, j = k & 7;
    WF[((ks * 64) + q * 16 + n) * 8 + j] =
        (n < OUTN) ? f2bf(Wout[k * OUTN + n]) : (ushort_t)0;
  }
}

// v9 structure (wave = 128 rows x 32 cols, NT=2, frag-major A) with the
// rolling-b deepened from depth-1 to a BATCH-8 register window b0..b7
// (in-place refill): all 8 mt-frags of the current ks live in regs; each
// b_mt's reload for ks+1 issues right after its 2 consuming MFMAs ->
// ~16 MFMAs (~78 cy) of cover per ds_read instead of 2 (~10 cy).
// Regs: acc 64 + b 32 + wf 16 + addr ~12 = ~124 <= 128 @ (512,4).
__global__ __launch_bounds__(512, 4) void fused_kernel(
    const float* __restrict__ x, const float* __restrict__ bias,
    const float* __restrict__ bout, const ushort_t* __restrict__ ATF,
    const ushort_t* __restrict__ WF, float* __restrict__ out) {
  __shared__ ushort_t hbuf[MROWS * HSTRIDE];  // 67584 B -> 2 blocks/CU

  const int tid  = threadIdx.x;
  const int wave = tid >> 6;     // 0..7: N-cols [wave*32, wave*32+32)
  const int lane = tid & 63;
  const int quad = lane >> 4;
  const int l16  = lane & 15;
  const long row0 = (long)blockIdx.x * MROWS;

  // ---- stage x tile (128 x 256 fp32) -> bf16 LDS ----
  const float4* xv = (const float4*)(x + row0 * DD);
#pragma unroll
  for (int i = 0; i < 16; i++) {
    int f  = tid + i * 512;      // 0..8191 float4s, 64 per row
    int r  = f >> 6;
    int c4 = f & 63;
    float4 v = xv[r * 64 + c4];
    uint2 w;
    w.x = pack_bf2(v.x, v.y);
    w.y = pack_bf2(v.z, v.w);
    *(uint2*)&hbuf[r * HSTRIDE + c4 * 4] = w;
  }
  __syncthreads();

  // ---- 3 levels. Operand-swap: Aop = AT rows (u), Bop = h rows (m).
  // D: col=l16 -> m_local, row=quad*4+r -> u_local. Bias folded into acc init.
#pragma unroll 1
  for (int l = 0; l < 3; l++) {
    const ushort_t* Ab   = ATF + l * 65536 + wave * 8192 + lane * 8;
    const ushort_t* hsrc = hbuf + l16 * HSTRIDE + quad * 8;

    floatx4 acc[8][NT];
#pragma unroll
    for (int nt = 0; nt < NT; nt++) {
      float4 bv = *(const float4*)&bias[l * DD + wave * 32 + nt * 16 + quad * 4];
      floatx4 ini = {bv.x, bv.y, bv.z, bv.w};
#pragma unroll
      for (int mt = 0; mt < 8; mt++) acc[mt][nt] = ini;
    }

    // batch-8 b window + depth-1 A
    short8 b0 = *(const short8*)&hsrc[0 * 16 * HSTRIDE];
    short8 b1 = *(const short8*)&hsrc[1 * 16 * HSTRIDE];
    short8 b2 = *(const short8*)&hsrc[2 * 16 * HSTRIDE];
    short8 b3 = *(const short8*)&hsrc[3 * 16 * HSTRIDE];
    short8 b4 = *(const short8*)&hsrc[4 * 16 * HSTRIDE];
    short8 b5 = *(const short8*)&hsrc[5 * 16 * HSTRIDE];
    short8 b6 = *(const short8*)&hsrc[6 * 16 * HSTRIDE];
    short8 b7 = *(const short8*)&hsrc[7 * 16 * HSTRIDE];
    short8 wf0 = *(const short8*)&Ab[0];
    short8 wf1 = *(const short8*)&Ab[4096];

#pragma unroll
    for (int ks = 0; ks < 8; ks++) {
      const int kn = ((ks + 1) & 7) * 32;   // LDS col offset of next ks (wraps)
      const int an = ((ks + 1) & 7) * 512;  // A offset of next ks (wraps)
      // each b_mt reloads for ks+1 right after its 2 consuming MFMAs:
      // ~16 MFMAs of cover before the ks+1 consumer needs it
      acc[0][0] = __builtin_amdgcn_mfma_f32_16x16x32_bf16(wf0, b0, acc[0][0], 0, 0, 0);
      acc[0][1] = __builtin_amdgcn_mfma_f32_16x16x32_bf16(wf1, b0, acc[0][1], 0, 0, 0);
      b0 = *(const short8*)&hsrc[0 * 16 * HSTRIDE + kn];
      acc[1][0] = __builtin_amdgcn_mfma_f32_16x16x32_bf16(wf0, b1, acc[1][0], 0, 0, 0);
      acc[1][1] = __builtin_amdgcn_mfma_f32_16x16x32_bf16(wf1, b1, acc[1][1], 0, 0, 0);
      b1 = *(const short8*)&hsrc[1 * 16 * HSTRIDE + kn];
      acc[2][0] = __builtin_amdgcn_mfma_f32_16x16x32_bf16(wf0, b2, acc[2][0], 0, 0, 0);
      acc[2][1] = __builtin_amdgcn_mfma_f32_16x16x32_bf16(wf1, b2, acc[2][1], 0, 0, 0);
      b2 = *(const short8*)&hsrc[2 * 16 * HSTRIDE + kn];
      acc[3][0] = __builtin_amdgcn_mfma_f32_16x16x32_bf16(wf0, b3, acc[3][0], 0, 0, 0);
      acc[3][1] = __builtin_amdgcn_mfma_f32_16x16x32_bf16(wf1, b3, acc[3][1], 0, 0, 0);
      b3 = *(const short8*)&hsrc[3 * 16 * HSTRIDE + kn];
      acc[4][0] = __builtin_amdgcn_mfma_f32_16x16x32_bf16(wf0, b4, acc[4][0], 0, 0, 0);
      acc[4][1] = __builtin_amdgcn_mfma_f32_16x16x32_bf16(wf1, b4, acc[4][1], 0, 0, 0);
      b4 = *(const short8*)&hsrc[4 * 16 * HSTRIDE + kn];
      acc[5][0] = __builtin_amdgcn_mfma_f32_16x16x32_bf16(wf0, b5, acc[5][0], 0, 0, 0);
      acc[5][1] = __builtin_amdgcn_mfma_f32_16x16x32_bf16(wf1, b5, acc[5][1], 0, 0, 0);
      b5 = *(const short8*)&hsrc[5 * 16 * HSTRIDE + kn];
      acc[6][0] = __builtin_amdgcn_mfma_f32_16x16x32_bf16(wf0, b6, acc[6][0], 0, 0, 0);
      acc[6][1] = __builtin_amdgcn_mfma_f32_16x16x32_bf16(wf1, b6, acc[6][1], 0, 0, 0);
      b6 = *(const short8*)&hsrc[6 * 16 * HSTRIDE + kn];
      acc[7][0] = __builtin_amdgcn_mfma_f32_16x16x32_bf16(wf0, b7, acc[7][0], 0, 0, 0);
      acc[7][1] = __builtin_amdgcn_mfma_f32_16x16x32_bf16(wf1, b7, acc[7][1], 0, 0, 0);
      b7 = *(const short8*)&hsrc[7 * 16 * HSTRIDE + kn];
      wf0 = *(const short8*)&Ab[an];
      wf1 = *(const short8*)&Ab[4096 + an];
    }
    __syncthreads();  // all hbuf reads done before overwrite

    // epilogue: lane holds 4 consecutive u for row m = mt*16+l16 -> 8B writes
#pragma unroll
    for (int nt = 0; nt < NT; nt++) {
#pragma unroll
      for (int mt = 0; mt < 8; mt++) {
        uint2 w;
        w.x = pack_bf2(fast_tanh(acc[mt][nt][0]), fast_tanh(acc[mt][nt][1]));
        w.y = pack_bf2(fast_tanh(acc[mt][nt][2]), fast_tanh(acc[mt][nt][3]));
        *(uint2*)&hbuf[(mt * 16 + l16) * HSTRIDE + wave * 32 + nt * 16 + quad * 4] = w;
      }
    }
    __syncthreads();
  }

  // ---- final: Aop = WF rows (o), frag-major; 16 rows per wave ----
  short8 wof[8];
#pragma unroll
  for (int ks = 0; ks < 8; ks++)
    wof[ks] = *(const short8*)&WF[ks * 512 + lane * 8];

  floatx4 accf = {0.f, 0.f, 0.f, 0.f};
#pragma unroll
  for (int ks = 0; ks < 8; ks++) {
    short8 bfr = *(const short8*)&hbuf[(wave * 16 + l16) * HSTRIDE + ks * 32 + quad * 8];
    accf = __builtin_amdgcn_mfma_f32_16x16x32_bf16(wof[ks], bfr, accf, 0, 0, 0);
  }
  const long obase = (row0 + wave * 16 + l16) * OUTN;
  if (quad < 2) {
    float4 p = {accf[0] + bout[quad * 4 + 0], accf[1] + bout[quad * 4 + 1],
                accf[2] + bout[quad * 4 + 2], accf[3] + bout[quad * 4 + 3]};
    *(float4*)&out[obase + quad * 4] = p;
  } else if (quad == 2) {
    float2 p = {accf[0] + bout[8], accf[1] + bout[9]};
    *(float2*)&out[obase + 8] = p;
  }
}

extern "C" void kernel_launch(void* const* d_in, const int* in_sizes, int n_in,
                              void* d_out, int out_size, void* d_ws, size_t ws_size,
                              hipStream_t stream) {
  const float* x    = (const float*)d_in[0];   // (131072, 256) fp32
  const int*   idx  = (const int*)d_in[1];     // (3, 4, 128) int32
  const float* W    = (const float*)d_in[2];   // (3, 4, 128, 64) fp32
  const float* b    = (const float*)d_in[3];   // (3, 4, 64) fp32
  const float* Wout = (const float*)d_in[4];   // (256, 10) fp32
  const float* bout = (const float*)d_in[5];   // (10,) fp32
  float* out = (float*)d_out;                  // (131072, 10) fp32

  ushort_t* ATF = (ushort_t*)d_ws;             // 3*16*8*64*8 bf16 = 384 KB
  ushort_t* WF  = ATF + LL * 16 * 8 * 64 * 8;  // 8*64*8 bf16 = 8 KB

  prep_kernel<<<LL * DD + 16, 256, 0, stream>>>(idx, W, Wout, ATF, WF);
  fused_kernel<<<131072 / MROWS, 512, 0, stream>>>(x, b, bout, ATF, WF, out);
}

// Round 11
// 247.898 us; speedup vs baseline: 1.0410x; 1.0410x over previous
//
#include <hip/hip_runtime.h>

typedef unsigned short ushort_t;
typedef __attribute__((ext_vector_type(8))) short short8;
typedef __attribute__((ext_vector_type(4))) float floatx4;

#define DD 256
#define LL 3
#define GG 4
#define KK 128
#define UU 64
#define OUTN 10
#define HSTRIDE 264   // 256 + 8 bf16 pad; 528B row stride
#define MROWS 128     // rows per block
#define NT 2          // 16-col tiles per wave (8 waves x 32 cols = 256)

__device__ __forceinline__ ushort_t f2bf(float f) {
  unsigned u = __builtin_bit_cast(unsigned, f);
  u = (u + 0x7FFFu + ((u >> 16) & 1u)) >> 16;
  return (ushort_t)u;
}

// pack two f32 -> two bf16: 2 adds + 1 v_perm_b32
__device__ __forceinline__ unsigned pack_bf2(float lo, float hi) {
  unsigned a = __builtin_bit_cast(unsigned, hi) + 0x8000u;
  unsigned b = __builtin_bit_cast(unsigned, lo) + 0x8000u;
  return __builtin_amdgcn_perm(a, b, 0x07060302u);
}

// tanh(x) = 1 - 2/(e^{2x}+1); branch-free, exact at overflow
__device__ __forceinline__ float fast_tanh(float x) {
  float e = __builtin_amdgcn_exp2f(x * 2.885390081777927f);
  return __builtin_fmaf(-2.0f, __builtin_amdgcn_rcpf(e + 1.0f), 1.0f);
}

// FRAG-MAJOR operand layouts (r9, kept):
// ATF[l][T][ks][lane][8] bf16, T = n>>4 (16 col-tiles), ks = k>>5,
// lane = quad*16 + l16, elem j -> (n = T*16 + l16, k = ks*32 + quad*8 + j).
// A-fragment load in fused = one contiguous 1KB global_load_dwordx4 per wave.
// WF[ks][lane][8] likewise for W_out^T (o = l16 rows, o<10 else 0).
__global__ __launch_bounds__(256) void prep_kernel(
    const int* __restrict__ idx, const float* __restrict__ W,
    const float* __restrict__ Wout, ushort_t* __restrict__ ATF,
    ushort_t* __restrict__ WF) {
  int b = blockIdx.x;
  int t = threadIdx.x;
  if (b < LL * DD) {
    int l = b >> 8, n = b & 255, g = n >> 6, u = n & 63;
    __shared__ int sidx[KK];
    __shared__ float sw[KK];
    if (t < KK) {
      sidx[t] = idx[(l * GG + g) * KK + t];
      sw[t]   = W[((size_t)((l * GG + g) * KK + t)) * UU + u];
    }
    __syncthreads();
    float s = 0.f;
#pragma unroll 8
    for (int j = 0; j < KK; j++) s += (sidx[j] == t) ? sw[j] : 0.f;
    // scatter into frag-major position (k = t)
    int T = n >> 4, nl = n & 15;
    int ks = t >> 5, q = (t >> 3) & 3, j = t & 7;
    ATF[((((l * 16 + T) * 8 + ks) * 64) + q * 16 + nl) * 8 + j] = f2bf(s);
  } else {
    int e2 = (b - LL * DD) * 256 + t;
    int n = e2 >> 8, k = e2 & 255;   // n = output col (o), k = input dim
    int ks = k >> 5, q = (k >> 3) & 3, j = k & 7;
    WF[((ks * 64) + q * 16 + n) * 8 + j] =
        (n < OUTN) ? f2bf(Wout[k * OUTN + n]) : (ushort_t)0;
  }
}

// v9 structure (wave = 128 rows x 32 cols, NT=2, frag-major A) with the
// rolling-b deepened from depth-1 to a DEPTH-4 WINDOW b0..b3 (16 VGPR):
// the 8 mt-slots per ks rotate through 4 buffers; each reload is issued
// 4 MFMA-pairs (~39 cy + slot waits) before its consumer, so 4 ds_reads
// are always in flight. Steady-state slot ~30cy -> per-wave MFMA duty
// ~33%, x4 waves/SIMD -> pipe-fed. A prefetch (wfn) issues early in the
// ks body (14 MFMAs of cover vs ~200cy L2).
// Regs: acc 64 (AGPR) + b 16 + wf/wfn 16 + addr -> fits the 64-arch cap
// at (512,4); v10's batch-8 (+16 more) spilled (WRITE_SIZE 21.7MB).
__global__ __launch_bounds__(512, 4) void fused_kernel(
    const float* __restrict__ x, const float* __restrict__ bias,
    const float* __restrict__ bout, const ushort_t* __restrict__ ATF,
    const ushort_t* __restrict__ WF, float* __restrict__ out) {
  __shared__ ushort_t hbuf[MROWS * HSTRIDE];  // 67584 B -> 2 blocks/CU

  const int tid  = threadIdx.x;
  const int wave = tid >> 6;     // 0..7: N-cols [wave*32, wave*32+32)
  const int lane = tid & 63;
  const int quad = lane >> 4;
  const int l16  = lane & 15;
  const long row0 = (long)blockIdx.x * MROWS;

  // ---- stage x tile (128 x 256 fp32) -> bf16 LDS ----
  const float4* xv = (const float4*)(x + row0 * DD);
#pragma unroll
  for (int i = 0; i < 16; i++) {
    int f  = tid + i * 512;      // 0..8191 float4s, 64 per row
    int r  = f >> 6;
    int c4 = f & 63;
    float4 v = xv[r * 64 + c4];
    uint2 w;
    w.x = pack_bf2(v.x, v.y);
    w.y = pack_bf2(v.z, v.w);
    *(uint2*)&hbuf[r * HSTRIDE + c4 * 4] = w;
  }
  __syncthreads();

  // ---- 3 levels. Operand-swap: Aop = AT rows (u), Bop = h rows (m).
  // D: col=l16 -> m_local, row=quad*4+r -> u_local. Bias folded into acc init.
#pragma unroll 1
  for (int l = 0; l < 3; l++) {
    const ushort_t* Ab   = ATF + l * 65536 + wave * 8192 + lane * 8;
    const ushort_t* hsrc = hbuf + l16 * HSTRIDE + quad * 8;

    floatx4 acc[8][NT];
#pragma unroll
    for (int nt = 0; nt < NT; nt++) {
      float4 bv = *(const float4*)&bias[l * DD + wave * 32 + nt * 16 + quad * 4];
      floatx4 ini = {bv.x, bv.y, bv.z, bv.w};
#pragma unroll
      for (int mt = 0; mt < 8; mt++) acc[mt][nt] = ini;
    }

    // depth-4 b window + early-prefetch A
    short8 b0 = *(const short8*)&hsrc[0 * 16 * HSTRIDE];
    short8 b1 = *(const short8*)&hsrc[1 * 16 * HSTRIDE];
    short8 b2 = *(const short8*)&hsrc[2 * 16 * HSTRIDE];
    short8 b3 = *(const short8*)&hsrc[3 * 16 * HSTRIDE];
    short8 wf0 = *(const short8*)&Ab[0];
    short8 wf1 = *(const short8*)&Ab[4096];
    short8 wfn0, wfn1;

#pragma unroll
    for (int ks = 0; ks < 8; ks++) {
      const int kc = ks * 32;               // current ks LDS col offset
      const int kn = ((ks + 1) & 7) * 32;   // next ks (wraps; ks=7 reloads dead)
      const int an = ((ks + 1) & 7) * 512;  // next ks A offset (wraps)
      // slot 0: consume b0(mt0), reload as mt4 (consumed 4 slots later)
      acc[0][0] = __builtin_amdgcn_mfma_f32_16x16x32_bf16(wf0, b0, acc[0][0], 0, 0, 0);
      acc[0][1] = __builtin_amdgcn_mfma_f32_16x16x32_bf16(wf1, b0, acc[0][1], 0, 0, 0);
      b0 = *(const short8*)&hsrc[4 * 16 * HSTRIDE + kc];
      wfn0 = *(const short8*)&Ab[an];       // A prefetch: 14 MFMAs of cover
      acc[1][0] = __builtin_amdgcn_mfma_f32_16x16x32_bf16(wf0, b1, acc[1][0], 0, 0, 0);
      acc[1][1] = __builtin_amdgcn_mfma_f32_16x16x32_bf16(wf1, b1, acc[1][1], 0, 0, 0);
      b1 = *(const short8*)&hsrc[5 * 16 * HSTRIDE + kc];
      wfn1 = *(const short8*)&Ab[4096 + an];
      acc[2][0] = __builtin_amdgcn_mfma_f32_16x16x32_bf16(wf0, b2, acc[2][0], 0, 0, 0);
      acc[2][1] = __builtin_amdgcn_mfma_f32_16x16x32_bf16(wf1, b2, acc[2][1], 0, 0, 0);
      b2 = *(const short8*)&hsrc[6 * 16 * HSTRIDE + kc];
      acc[3][0] = __builtin_amdgcn_mfma_f32_16x16x32_bf16(wf0, b3, acc[3][0], 0, 0, 0);
      acc[3][1] = __builtin_amdgcn_mfma_f32_16x16x32_bf16(wf1, b3, acc[3][1], 0, 0, 0);
      b3 = *(const short8*)&hsrc[7 * 16 * HSTRIDE + kc];
      // slot 4..7: consume the reloads (issued 4 MFMA-pairs earlier),
      // refill with next-ks mt0..3
      acc[4][0] = __builtin_amdgcn_mfma_f32_16x16x32_bf16(wf0, b0, acc[4][0], 0, 0, 0);
      acc[4][1] = __builtin_amdgcn_mfma_f32_16x16x32_bf16(wf1, b0, acc[4][1], 0, 0, 0);
      b0 = *(const short8*)&hsrc[0 * 16 * HSTRIDE + kn];
      acc[5][0] = __builtin_amdgcn_mfma_f32_16x16x32_bf16(wf0, b1, acc[5][0], 0, 0, 0);
      acc[5][1] = __builtin_amdgcn_mfma_f32_16x16x32_bf16(wf1, b1, acc[5][1], 0, 0, 0);
      b1 = *(const short8*)&hsrc[1 * 16 * HSTRIDE + kn];
      acc[6][0] = __builtin_amdgcn_mfma_f32_16x16x32_bf16(wf0, b2, acc[6][0], 0, 0, 0);
      acc[6][1] = __builtin_amdgcn_mfma_f32_16x16x32_bf16(wf1, b2, acc[6][1], 0, 0, 0);
      b2 = *(const short8*)&hsrc[2 * 16 * HSTRIDE + kn];
      acc[7][0] = __builtin_amdgcn_mfma_f32_16x16x32_bf16(wf0, b3, acc[7][0], 0, 0, 0);
      acc[7][1] = __builtin_amdgcn_mfma_f32_16x16x32_bf16(wf1, b3, acc[7][1], 0, 0, 0);
      b3 = *(const short8*)&hsrc[3 * 16 * HSTRIDE + kn];
      wf0 = wfn0; wf1 = wfn1;
    }
    __syncthreads();  // all hbuf reads done before overwrite

    // epilogue: lane holds 4 consecutive u for row m = mt*16+l16 -> 8B writes
#pragma unroll
    for (int nt = 0; nt < NT; nt++) {
#pragma unroll
      for (int mt = 0; mt < 8; mt++) {
        uint2 w;
        w.x = pack_bf2(fast_tanh(acc[mt][nt][0]), fast_tanh(acc[mt][nt][1]));
        w.y = pack_bf2(fast_tanh(acc[mt][nt][2]), fast_tanh(acc[mt][nt][3]));
        *(uint2*)&hbuf[(mt * 16 + l16) * HSTRIDE + wave * 32 + nt * 16 + quad * 4] = w;
      }
    }
    __syncthreads();
  }

  // ---- final: Aop = WF rows (o), frag-major; 16 rows per wave ----
  short8 wof[8];
#pragma unroll
  for (int ks = 0; ks < 8; ks++)
    wof[ks] = *(const short8*)&WF[ks * 512 + lane * 8];

  floatx4 accf = {0.f, 0.f, 0.f, 0.f};
#pragma unroll
  for (int ks = 0; ks < 8; ks++) {
    short8 bfr = *(const short8*)&hbuf[(wave * 16 + l16) * HSTRIDE + ks * 32 + quad * 8];
    accf = __builtin_amdgcn_mfma_f32_16x16x32_bf16(wof[ks], bfr, accf, 0, 0, 0);
  }
  const long obase = (row0 + wave * 16 + l16) * OUTN;
  if (quad < 2) {
    float4 p = {accf[0] + bout[quad * 4 + 0], accf[1] + bout[quad * 4 + 1],
                accf[2] + bout[quad * 4 + 2], accf[3] + bout[quad * 4 + 3]};
    *(float4*)&out[obase + quad * 4] = p;
  } else if (quad == 2) {
    float2 p = {accf[0] + bout[8], accf[1] + bout[9]};
    *(float2*)&out[obase + 8] = p;
  }
}

extern "C" void kernel_launch(void* const* d_in, const int* in_sizes, int n_in,
                              void* d_out, int out_size, void* d_ws, size_t ws_size,
                              hipStream_t stream) {
  const float* x    = (const float*)d_in[0];   // (131072, 256) fp32
  const int*   idx  = (const int*)d_in[1];     // (3, 4, 128) int32
  const float* W    = (const float*)d_in[2];   // (3, 4, 128, 64) fp32
  const float* b    = (const float*)d_in[3];   // (3, 4, 64) fp32
  const float* Wout = (const float*)d_in[4];   // (256, 10) fp32
  const float* bout = (const float*)d_in[5];   // (10,) fp32
  float* out = (float*)d_out;                  // (131072, 10) fp32

  ushort_t* ATF = (ushort_t*)d_ws;             // 3*16*8*64*8 bf16 = 384 KB
  ushort_t* WF  = ATF + LL * 16 * 8 * 64 * 8;  // 8*64*8 bf16 = 8 KB

  prep_kernel<<<LL * DD + 16, 256, 0, stream>>>(idx, W, Wout, ATF, WF);
  fused_kernel<<<131072 / MROWS, 512, 0, stream>>>(x, b, bout, ATF, WF, out);
}